// Round 3
// baseline (742.585 us; speedup 1.0000x reference)
//
#include <hip/hip_runtime.h>
#include <math.h>

typedef unsigned short u16;
typedef unsigned int u32;
typedef __attribute__((ext_vector_type(8))) short short8;      // bf16x8 MFMA frag
typedef __attribute__((ext_vector_type(8))) unsigned short u16x8;
typedef __attribute__((ext_vector_type(4))) float f32x4;       // MFMA acc

static constexpr int B_   = 32;
static constexpr int C_   = 2048;
static constexpr int N_   = 576;   // H*W
static constexpr int MID_ = 256;
static constexpr int M_   = 512;   // 2*MID

__device__ __forceinline__ u16 bf16_rne(float x) {
  u32 u = __float_as_uint(x);
  return (u16)((u + 0x7FFFu + ((u >> 16) & 1u)) >> 16);
}
__device__ __forceinline__ float bf16f(u16 h) {
  return __uint_as_float(((u32)h) << 16);
}

// global -> LDS direct DMA, 16 B per lane (wave-uniform LDS base + lane*16)
typedef const __attribute__((address_space(1))) unsigned int gu32_t;
typedef __attribute__((address_space(3))) unsigned int lu32_t;
__device__ __forceinline__ void gl16(const void* g, void* l) {
  __builtin_amdgcn_global_load_lds((gu32_t*)g, (lu32_t*)l, 16, 0, 0);
}

// ---------------------------------------------------------------------------
// Prep W: Wcat = [W1;W2] (512x2048) -> split bf16 hi/lo, k-contiguous.
// ---------------------------------------------------------------------------
__global__ __launch_bounds__(256) void k_prep_w(
    const float* __restrict__ W1, const float* __restrict__ W2,
    u16* __restrict__ Wh, u16* __restrict__ Wl) {
  const int idx = blockIdx.x * 256 + threadIdx.x;
  const int e0 = idx * 4;
  const int m = e0 >> 11;
  const int c = e0 & 2047;
  const float* src = (m < MID_) ? &W1[(size_t)m * C_ + c]
                                : &W2[(size_t)(m - MID_) * C_ + c];
  const float4 v = *(const float4*)src;
  const float f[4] = {v.x, v.y, v.z, v.w};
  u16 h[4], l[4];
#pragma unroll
  for (int i = 0; i < 4; ++i) {
    h[i] = bf16_rne(f[i]);
    l[i] = bf16_rne(f[i] - bf16f(h[i]));
  }
  *(ushort4*)&Wh[e0] = make_ushort4(h[0], h[1], h[2], h[3]);
  *(ushort4*)&Wl[e0] = make_ushort4(l[0], l[1], l[2], l[3]);
}

// ---------------------------------------------------------------------------
// Prep feat: feat[b][c][n] fp32 -> fTh/fTl [b][n][c] split bf16 (transpose).
// 64x64 tile per block via LDS; grid (32 ctiles, 9 ntiles, bc).
// ---------------------------------------------------------------------------
__global__ __launch_bounds__(256) void k_prep_feat(
    const float* __restrict__ feat, u16* __restrict__ fTh,
    u16* __restrict__ fTl) {
  const int c0 = blockIdx.x * 64;
  const int n0 = blockIdx.y * 64;
  const int b  = blockIdx.z;
  __shared__ float Ts[64][65];  // pitch 65: phase-2 reads 2-way, free
  const float* src = feat + ((size_t)b * C_ + c0) * N_ + n0;
  const int t = threadIdx.x;
  const int tr  = t >> 4;
  const int tc4 = (t & 15) * 4;
#pragma unroll
  for (int e = 0; e < 4; ++e) {
    const int c = tr + e * 16;
    const float4 v = *(const float4*)&src[(size_t)c * N_ + tc4];
    Ts[c][tc4] = v.x; Ts[c][tc4 + 1] = v.y;
    Ts[c][tc4 + 2] = v.z; Ts[c][tc4 + 3] = v.w;
  }
  __syncthreads();
  const int co = (t & 7) * 8;
#pragma unroll
  for (int p = 0; p < 2; ++p) {
    const int n = (t >> 3) + p * 32;
    u16x8 hv, lv;
#pragma unroll
    for (int e = 0; e < 8; ++e) {
      const float x = Ts[co + e][n];
      const u16 h = bf16_rne(x);
      hv[e] = h;
      lv[e] = bf16_rne(x - bf16f(h));
    }
    const size_t off = ((size_t)b * N_ + n0 + n) * C_ + c0 + co;
    *(u16x8*)&fTh[off] = hv;
    *(u16x8*)&fTl[off] = lv;
  }
}

// ---------------------------------------------------------------------------
// Prep cam: fp32 -> bf16 (layout unchanged; k=j already contiguous).
// ---------------------------------------------------------------------------
__global__ __launch_bounds__(256) void k_prep_cam(
    const float* __restrict__ cam, u16* __restrict__ camh) {
  const int e0 = (blockIdx.x * 256 + threadIdx.x) * 8;
  const float4 a = *(const float4*)&cam[e0];
  const float4 b = *(const float4*)&cam[e0 + 4];
  u16x8 hv;
  hv[0] = bf16_rne(a.x); hv[1] = bf16_rne(a.y);
  hv[2] = bf16_rne(a.z); hv[3] = bf16_rne(a.w);
  hv[4] = bf16_rne(b.x); hv[5] = bf16_rne(b.y);
  hv[6] = bf16_rne(b.z); hv[7] = bf16_rne(b.w);
  *(u16x8*)&camh[e0] = hv;
}

// ---------------------------------------------------------------------------
// K1: f12[b][n][m] = sum_c fT[b][n][c] * Wcat[m][c], 3-term split MFMA.
// Pure global_load_lds staging; 128x128 tile, BK=32; out as split h/l u16.
// ---------------------------------------------------------------------------
__global__ __launch_bounds__(256) void k_f12(
    const u16* __restrict__ fTh, const u16* __restrict__ fTl,
    const u16* __restrict__ Wh, const u16* __restrict__ Wl,
    u16* __restrict__ f12h, u16* __restrict__ f12l) {
  const int mt = blockIdx.x;  // 0..3
  const int nt = blockIdx.y;  // 0..4
  const int b  = blockIdx.z;
  __shared__ __align__(16) u16 Ah[128 * 32], Al[128 * 32];
  __shared__ __align__(16) u16 Bh[128 * 32], Bl[128 * 32];
  const int t = threadIdx.x, lane = t & 63, w = t >> 6;
  const int wm = (w >> 1) * 64, wn = (w & 1) * 64;
  const int n0 = nt * 128, m0 = mt * 128;
  const int rrow = lane >> 2;
  const int koff = (lane & 3) * 8;  // u16 units (16 B)
  const int r0 = w * 32;
  const u16* fTh_b = fTh + (size_t)b * N_ * C_;
  const u16* fTl_b = fTl + (size_t)b * N_ * C_;

  f32x4 acc[4][4];
#pragma unroll
  for (int i = 0; i < 4; ++i)
#pragma unroll
    for (int j = 0; j < 4; ++j) acc[i][j] = (f32x4)(0.0f);

  for (int k0 = 0; k0 < C_; k0 += 32) {
#pragma unroll
    for (int q = 0; q < 2; ++q) {
      const int row = r0 + q * 16 + rrow;
      const int ng = min(n0 + row, N_ - 1);
      const int mg = m0 + row;
      const int lb = (r0 + q * 16) * 32;  // wave-uniform LDS base (u16 idx)
      gl16(&fTh_b[(size_t)ng * C_ + k0 + koff], &Ah[lb]);
      gl16(&fTl_b[(size_t)ng * C_ + k0 + koff], &Al[lb]);
      gl16(&Wh[(size_t)mg * C_ + k0 + koff], &Bh[lb]);
      gl16(&Wl[(size_t)mg * C_ + k0 + koff], &Bl[lb]);
    }
    __syncthreads();
    const int fr = lane & 15, qo = (lane >> 4) * 8;
    short8 afh[4], afl[4], bfh[4], bfl[4];
#pragma unroll
    for (int i = 0; i < 4; ++i) {
      afh[i] = *(const short8*)&Ah[(wm + 16 * i + fr) * 32 + qo];
      afl[i] = *(const short8*)&Al[(wm + 16 * i + fr) * 32 + qo];
      bfh[i] = *(const short8*)&Bh[(wn + 16 * i + fr) * 32 + qo];
      bfl[i] = *(const short8*)&Bl[(wn + 16 * i + fr) * 32 + qo];
    }
#pragma unroll
    for (int i = 0; i < 4; ++i)
#pragma unroll
      for (int j = 0; j < 4; ++j) {
        acc[i][j] = __builtin_amdgcn_mfma_f32_16x16x32_bf16(afh[i], bfh[j], acc[i][j], 0, 0, 0);
        acc[i][j] = __builtin_amdgcn_mfma_f32_16x16x32_bf16(afh[i], bfl[j], acc[i][j], 0, 0, 0);
        acc[i][j] = __builtin_amdgcn_mfma_f32_16x16x32_bf16(afl[i], bfh[j], acc[i][j], 0, 0, 0);
      }
    __syncthreads();
  }
#pragma unroll
  for (int i = 0; i < 4; ++i) {
    const int nb = n0 + wm + 16 * i + ((lane >> 4) * 4);
#pragma unroll
    for (int j = 0; j < 4; ++j) {
      const int m = m0 + wn + 16 * j + (lane & 15);
#pragma unroll
      for (int r = 0; r < 4; ++r) {
        const int n = nb + r;
        if (n < N_) {
          const float x = acc[i][j][r];
          const u16 h = bf16_rne(x);
          f12h[((size_t)b * N_ + n) * M_ + m] = h;
          f12l[((size_t)b * N_ + n) * M_ + m] = bf16_rne(x - bf16f(h));
        }
      }
    }
  }
}

// ---------------------------------------------------------------------------
// K2: logits[b][i][j] = sum_m f12[b][i][m] * f12[b][j][m+256], 3-term split.
// ---------------------------------------------------------------------------
__global__ __launch_bounds__(256) void k_logits(
    const u16* __restrict__ f12h, const u16* __restrict__ f12l,
    float* __restrict__ logits) {
  const int jt = blockIdx.x;  // 0..4
  const int it = blockIdx.y;  // 0..4
  const int b  = blockIdx.z;
  __shared__ __align__(16) u16 Ah[128 * 32], Al[128 * 32];
  __shared__ __align__(16) u16 Bh[128 * 32], Bl[128 * 32];
  const int t = threadIdx.x, lane = t & 63, w = t >> 6;
  const int wm = (w >> 1) * 64, wn = (w & 1) * 64;
  const int i0 = it * 128, j0 = jt * 128;
  const int rrow = lane >> 2;
  const int koff = (lane & 3) * 8;
  const int r0 = w * 32;
  const u16* fh_b = f12h + (size_t)b * N_ * M_;
  const u16* fl_b = f12l + (size_t)b * N_ * M_;

  f32x4 acc[4][4];
#pragma unroll
  for (int i = 0; i < 4; ++i)
#pragma unroll
    for (int j = 0; j < 4; ++j) acc[i][j] = (f32x4)(0.0f);

  for (int k0 = 0; k0 < MID_; k0 += 32) {
#pragma unroll
    for (int q = 0; q < 2; ++q) {
      const int row = r0 + q * 16 + rrow;
      const int ig = min(i0 + row, N_ - 1);
      const int jg = min(j0 + row, N_ - 1);
      const int lb = (r0 + q * 16) * 32;
      gl16(&fh_b[(size_t)ig * M_ + k0 + koff], &Ah[lb]);
      gl16(&fl_b[(size_t)ig * M_ + k0 + koff], &Al[lb]);
      gl16(&fh_b[(size_t)jg * M_ + MID_ + k0 + koff], &Bh[lb]);
      gl16(&fl_b[(size_t)jg * M_ + MID_ + k0 + koff], &Bl[lb]);
    }
    __syncthreads();
    const int fr = lane & 15, qo = (lane >> 4) * 8;
    short8 afh[4], afl[4], bfh[4], bfl[4];
#pragma unroll
    for (int i = 0; i < 4; ++i) {
      afh[i] = *(const short8*)&Ah[(wm + 16 * i + fr) * 32 + qo];
      afl[i] = *(const short8*)&Al[(wm + 16 * i + fr) * 32 + qo];
      bfh[i] = *(const short8*)&Bh[(wn + 16 * i + fr) * 32 + qo];
      bfl[i] = *(const short8*)&Bl[(wn + 16 * i + fr) * 32 + qo];
    }
#pragma unroll
    for (int i = 0; i < 4; ++i)
#pragma unroll
      for (int j = 0; j < 4; ++j) {
        acc[i][j] = __builtin_amdgcn_mfma_f32_16x16x32_bf16(afh[i], bfh[j], acc[i][j], 0, 0, 0);
        acc[i][j] = __builtin_amdgcn_mfma_f32_16x16x32_bf16(afh[i], bfl[j], acc[i][j], 0, 0, 0);
        acc[i][j] = __builtin_amdgcn_mfma_f32_16x16x32_bf16(afl[i], bfh[j], acc[i][j], 0, 0, 0);
      }
    __syncthreads();
  }
  float* log_b = logits + (size_t)b * N_ * N_;
#pragma unroll
  for (int i = 0; i < 4; ++i) {
    const int ibase = i0 + wm + 16 * i + ((lane >> 4) * 4);
#pragma unroll
    for (int j = 0; j < 4; ++j) {
      const int jj = j0 + wn + 16 * j + (lane & 15);
      if (jj < N_) {
#pragma unroll
        for (int r = 0; r < 4; ++r) {
          const int ii = ibase + r;
          if (ii < N_) log_b[(size_t)ii * N_ + jj] = acc[i][j][r];
        }
      }
    }
  }
}

// ---------------------------------------------------------------------------
// K3: row softmax (576) — one wave per row; fp32 in, bf16 out.
// ---------------------------------------------------------------------------
__global__ __launch_bounds__(64) void k_softmax(
    const float* __restrict__ logits, u16* __restrict__ attn) {
  const int row = blockIdx.x;
  const float* p = logits + (size_t)row * N_;
  u16* o = attn + (size_t)row * N_;
  const int lane = threadIdx.x;
  float v[9];
  float mx = -INFINITY;
#pragma unroll
  for (int q = 0; q < 9; ++q) {
    v[q] = p[lane + q * 64];
    mx = fmaxf(mx, v[q]);
  }
#pragma unroll
  for (int off = 32; off > 0; off >>= 1) mx = fmaxf(mx, __shfl_down(mx, off));
  mx = __shfl(mx, 0);
  float s = 0.f;
#pragma unroll
  for (int q = 0; q < 9; ++q) {
    v[q] = __expf(v[q] - mx);
    s += v[q];
  }
#pragma unroll
  for (int off = 32; off > 0; off >>= 1) s += __shfl_down(s, off);
  s = __shfl(s, 0);
  const float inv = 1.0f / s;
#pragma unroll
  for (int q = 0; q < 9; ++q) o[lane + q * 64] = bf16_rne(v[q] * inv);
}

// ---------------------------------------------------------------------------
// K4: out[b][c][i] = alpha * sum_j attn[b][i][j]*camh[b][c][j] + cam[b][c][i]
// Single-term bf16 MFMA, pure global_load_lds staging.
// ---------------------------------------------------------------------------
__global__ __launch_bounds__(256) void k_out(
    const u16* __restrict__ camh, const u16* __restrict__ attn,
    const float* __restrict__ cam, const float* __restrict__ alpha_p,
    float* __restrict__ out) {
  const int ct = blockIdx.x;  // 0..15
  const int it = blockIdx.y;  // 0..4
  const int b  = blockIdx.z;
  __shared__ __align__(16) u16 As[128 * 32], Bs[128 * 32];
  const int t = threadIdx.x, lane = t & 63, w = t >> 6;
  const int wm = (w >> 1) * 64, wn = (w & 1) * 64;
  const int c0 = ct * 128, i0 = it * 128;
  const int rrow = lane >> 2;
  const int koff = (lane & 3) * 8;
  const int r0 = w * 32;
  const u16* camh_b = camh + (size_t)b * C_ * N_;
  const u16* attn_b = attn + (size_t)b * N_ * N_;

  f32x4 acc[4][4];
#pragma unroll
  for (int i = 0; i < 4; ++i)
#pragma unroll
    for (int j = 0; j < 4; ++j) acc[i][j] = (f32x4)(0.0f);

  for (int k0 = 0; k0 < N_; k0 += 32) {
#pragma unroll
    for (int q = 0; q < 2; ++q) {
      const int row = r0 + q * 16 + rrow;
      const int cg = c0 + row;
      const int ig = min(i0 + row, N_ - 1);
      const int lb = (r0 + q * 16) * 32;
      gl16(&camh_b[(size_t)cg * N_ + k0 + koff], &As[lb]);
      gl16(&attn_b[(size_t)ig * N_ + k0 + koff], &Bs[lb]);
    }
    __syncthreads();
    const int fr = lane & 15, qo = (lane >> 4) * 8;
    short8 af[4], bf[4];
#pragma unroll
    for (int i = 0; i < 4; ++i) {
      af[i] = *(const short8*)&As[(wm + 16 * i + fr) * 32 + qo];
      bf[i] = *(const short8*)&Bs[(wn + 16 * i + fr) * 32 + qo];
    }
#pragma unroll
    for (int i = 0; i < 4; ++i)
#pragma unroll
      for (int j = 0; j < 4; ++j)
        acc[i][j] = __builtin_amdgcn_mfma_f32_16x16x32_bf16(af[i], bf[j], acc[i][j], 0, 0, 0);
    __syncthreads();
  }
  const float alpha = *alpha_p;
  const float* cam_b = cam + (size_t)b * C_ * N_;
  float* out_b = out + (size_t)b * C_ * N_;
#pragma unroll
  for (int ii = 0; ii < 4; ++ii) {
    const int c = c0 + wm + 16 * ii + ((lane >> 4) * 4);
#pragma unroll
    for (int jj = 0; jj < 4; ++jj) {
      const int i = i0 + wn + 16 * jj + (lane & 15);
      if (i < N_) {
#pragma unroll
        for (int r = 0; r < 4; ++r) {
          const size_t off = (size_t)(c + r) * N_ + i;
          out_b[off] = alpha * acc[ii][jj][r] + cam_b[off];
        }
      }
    }
  }
}

// ---------------------------------------------------------------------------
extern "C" void kernel_launch(void* const* d_in, const int* in_sizes, int n_in,
                              void* d_out, int out_size, void* d_ws,
                              size_t ws_size, hipStream_t stream) {
  const float* cam   = (const float*)d_in[0];
  const float* feat  = (const float*)d_in[1];
  const float* W1    = (const float*)d_in[2];
  const float* W2    = (const float*)d_in[3];
  const float* alpha = (const float*)d_in[4];
  float* out = (float*)d_out;

  // Batch-chunked f12 stage adapts to ws_size (branch on constant => graph-safe).
  //   required(bc) = bc*4718592 (fT h+l) + 88604672 (f12 h/l + W h/l + logits)
  int bc = 8;
  if (ws_size >= (size_t)32 * 4718592 + 88604672) bc = 32;       // 228.5 MiB
  else if (ws_size >= (size_t)16 * 4718592 + 88604672) bc = 16;  // 156.5 MiB
  const int nc = B_ / bc;
  const size_t S = (size_t)bc * 4718592;

  char* ws = (char*)d_ws;
  u16*   fTh    = (u16*)ws;
  u16*   fTl    = (u16*)(ws + S / 2);
  u16*   f12h   = (u16*)(ws + S);
  u16*   f12l   = (u16*)(ws + S + 18874368);
  u16*   Wh     = (u16*)(ws + S + 37748736);
  u16*   Wl     = (u16*)(ws + S + 41943040);
  float* logits = (float*)(ws + S + 46137344);
  u16*   attn   = (u16*)ws;               // overlays fT (dead after last k_f12)
  u16*   camh   = (u16*)(ws + 21233664);  // overlays fT/f12/W/logits tails;
                                          // written only after softmax.

  k_prep_w<<<dim3(1024), 256, 0, stream>>>(W1, W2, Wh, Wl);
  for (int ci = 0; ci < nc; ++ci) {
    const float* feat_c = feat + (size_t)ci * bc * C_ * N_;
    u16* f12h_c = f12h + (size_t)ci * bc * N_ * M_;
    u16* f12l_c = f12l + (size_t)ci * bc * N_ * M_;
    k_prep_feat<<<dim3(32, 9, bc), 256, 0, stream>>>(feat_c, fTh, fTl);
    k_f12<<<dim3(4, 5, bc), 256, 0, stream>>>(fTh, fTl, Wh, Wl, f12h_c, f12l_c);
  }
  k_logits<<<dim3(5, 5, B_), 256, 0, stream>>>(f12h, f12l, logits);
  k_softmax<<<dim3(B_ * N_), 64, 0, stream>>>(logits, attn);
  k_prep_cam<<<dim3(18432), 256, 0, stream>>>(cam, camh);
  k_out<<<dim3(16, 5, B_), 256, 0, stream>>>(camh, attn, cam, alpha, out);
}

// Round 4
// 530.416 us; speedup vs baseline: 1.4000x; 1.4000x over previous
//
#include <hip/hip_runtime.h>
#include <math.h>

typedef unsigned short u16;
typedef unsigned int u32;
typedef _Float16 f16;
typedef __attribute__((ext_vector_type(8))) _Float16 f16x8;   // MFMA A/B frag
typedef __attribute__((ext_vector_type(4))) float f32x4;      // MFMA acc

static constexpr int B_   = 32;
static constexpr int C_   = 2048;
static constexpr int N_   = 576;    // H*W
static constexpr int MID_ = 256;
static constexpr int M_   = 512;    // 2*MID
static constexpr int NB_  = B_ * N_;  // 18432 = 144*128

// global -> LDS direct DMA, 16 B per lane (wave-uniform LDS base + lane*16)
typedef const __attribute__((address_space(1))) unsigned int gu32_t;
typedef __attribute__((address_space(3))) unsigned int lu32_t;
__device__ __forceinline__ void gl16(const void* g, void* l) {
  __builtin_amdgcn_global_load_lds((gu32_t*)g, (lu32_t*)l, 16, 0, 0);
}

// ---------------------------------------------------------------------------
// Prep W: Wcat = [W1;W2] (512x2048) -> fp16, k-contiguous.
// ---------------------------------------------------------------------------
__global__ __launch_bounds__(256) void k_prep_w(
    const float* __restrict__ W1, const float* __restrict__ W2,
    f16* __restrict__ Wc) {
  const int e0 = (blockIdx.x * 256 + threadIdx.x) * 8;
  const int m = e0 >> 11;
  const int c = e0 & 2047;
  const float* src = (m < MID_) ? &W1[(size_t)m * C_ + c]
                                : &W2[(size_t)(m - MID_) * C_ + c];
  const float4 a = *(const float4*)&src[0];
  const float4 b = *(const float4*)&src[4];
  f16x8 hv;
  hv[0] = (f16)a.x; hv[1] = (f16)a.y; hv[2] = (f16)a.z; hv[3] = (f16)a.w;
  hv[4] = (f16)b.x; hv[5] = (f16)b.y; hv[6] = (f16)b.z; hv[7] = (f16)b.w;
  *(f16x8*)&Wc[e0] = hv;
}

// ---------------------------------------------------------------------------
// Prep feat: feat[b][c][n] fp32 -> fT[(b*576+n)][c] fp16 (transpose).
// 64x64 tile via LDS; grid (32 ctiles, 9 ntiles, 32 b).
// ---------------------------------------------------------------------------
__global__ __launch_bounds__(256) void k_prep_feat(
    const float* __restrict__ feat, f16* __restrict__ fT) {
  const int c0 = blockIdx.x * 64;
  const int n0 = blockIdx.y * 64;
  const int b  = blockIdx.z;
  __shared__ float Ts[64][65];
  const float* src = feat + ((size_t)b * C_ + c0) * N_ + n0;
  const int t = threadIdx.x;
  const int tr  = t >> 4;
  const int tc4 = (t & 15) * 4;
#pragma unroll
  for (int e = 0; e < 4; ++e) {
    const int c = tr + e * 16;
    const float4 v = *(const float4*)&src[(size_t)c * N_ + tc4];
    Ts[c][tc4] = v.x; Ts[c][tc4 + 1] = v.y;
    Ts[c][tc4 + 2] = v.z; Ts[c][tc4 + 3] = v.w;
  }
  __syncthreads();
  const int co = (t & 7) * 8;
#pragma unroll
  for (int p = 0; p < 2; ++p) {
    const int n = (t >> 3) + p * 32;
    f16x8 hv;
#pragma unroll
    for (int e = 0; e < 8; ++e) hv[e] = (f16)Ts[co + e][n];
    *(f16x8*)&fT[((size_t)b * N_ + n0 + n) * C_ + c0 + co] = hv;
  }
}

// ---------------------------------------------------------------------------
// Prep cam: fp32 -> fp16 (layout unchanged; k=j contiguous).
// ---------------------------------------------------------------------------
__global__ __launch_bounds__(256) void k_prep_cam(
    const float* __restrict__ cam, f16* __restrict__ camh) {
  const int e0 = (blockIdx.x * 256 + threadIdx.x) * 8;
  const float4 a = *(const float4*)&cam[e0];
  const float4 b = *(const float4*)&cam[e0 + 4];
  f16x8 hv;
  hv[0] = (f16)a.x; hv[1] = (f16)a.y; hv[2] = (f16)a.z; hv[3] = (f16)a.w;
  hv[4] = (f16)b.x; hv[5] = (f16)b.y; hv[6] = (f16)b.z; hv[7] = (f16)b.w;
  *(f16x8*)&camh[e0] = hv;
}

// ---------------------------------------------------------------------------
// K1: f12[(b n)][m] = sum_c fT[(b n)][c] * Wcat[m][c]  — one flat GEMM,
// M=512, N=18432, K=2048. 128x128 tile, BK=32, single fp16 MFMA.
// Grid (4 mtiles, 144 ntiles); no edge clamps (exact fit).
// ---------------------------------------------------------------------------
__global__ __launch_bounds__(256) void k_f12(
    const f16* __restrict__ fT, const f16* __restrict__ Wc,
    f16* __restrict__ f12) {
  const int mt = blockIdx.x;  // 0..3
  const int nt = blockIdx.y;  // 0..143
  __shared__ __align__(16) f16 As[128 * 32], Bs[128 * 32];
  const int t = threadIdx.x, lane = t & 63, w = t >> 6;
  const int wm = (w >> 1) * 64, wn = (w & 1) * 64;
  const int n0 = nt * 128, m0 = mt * 128;
  const int rrow = lane >> 2;
  const int koff = (lane & 3) * 8;  // f16 units (16 B)
  const int r0 = w * 32;

  f32x4 acc[4][4];
#pragma unroll
  for (int i = 0; i < 4; ++i)
#pragma unroll
    for (int j = 0; j < 4; ++j) acc[i][j] = (f32x4)(0.0f);

  for (int k0 = 0; k0 < C_; k0 += 32) {
#pragma unroll
    for (int q = 0; q < 2; ++q) {
      const int row = r0 + q * 16 + rrow;
      const int lb = (r0 + q * 16) * 32;
      gl16(&fT[(size_t)(n0 + row) * C_ + k0 + koff], &As[lb]);
      gl16(&Wc[(size_t)(m0 + row) * C_ + k0 + koff], &Bs[lb]);
    }
    __syncthreads();
    const int fr = lane & 15, qo = (lane >> 4) * 8;
    f16x8 af[4], bf[4];
#pragma unroll
    for (int i = 0; i < 4; ++i) {
      af[i] = *(const f16x8*)&As[(wm + 16 * i + fr) * 32 + qo];
      bf[i] = *(const f16x8*)&Bs[(wn + 16 * i + fr) * 32 + qo];
    }
#pragma unroll
    for (int i = 0; i < 4; ++i)
#pragma unroll
      for (int j = 0; j < 4; ++j)
        acc[i][j] = __builtin_amdgcn_mfma_f32_16x16x32_f16(af[i], bf[j], acc[i][j], 0, 0, 0);
    __syncthreads();
  }
#pragma unroll
  for (int i = 0; i < 4; ++i) {
    const int nb = n0 + wm + 16 * i + ((lane >> 4) * 4);
#pragma unroll
    for (int j = 0; j < 4; ++j) {
      const int m = m0 + wn + 16 * j + (lane & 15);
#pragma unroll
      for (int r = 0; r < 4; ++r)
        f12[(size_t)(nb + r) * M_ + m] = (f16)acc[i][j][r];
    }
  }
}

// ---------------------------------------------------------------------------
// K2: logits[b][i][j] = sum_m f12[b*576+i][m] * f12[b*576+j][m+256].
// K=256, single fp16 MFMA. Grid (5 jt, 5 it, 32 b).
// ---------------------------------------------------------------------------
__global__ __launch_bounds__(256) void k_logits(
    const f16* __restrict__ f12, float* __restrict__ logits) {
  const int jt = blockIdx.x;
  const int it = blockIdx.y;
  const int b  = blockIdx.z;
  __shared__ __align__(16) f16 As[128 * 32], Bs[128 * 32];
  const int t = threadIdx.x, lane = t & 63, w = t >> 6;
  const int wm = (w >> 1) * 64, wn = (w & 1) * 64;
  const int i0 = it * 128, j0 = jt * 128;
  const int rrow = lane >> 2;
  const int koff = (lane & 3) * 8;
  const int r0 = w * 32;
  const f16* f_b = f12 + (size_t)b * N_ * M_;

  f32x4 acc[4][4];
#pragma unroll
  for (int i = 0; i < 4; ++i)
#pragma unroll
    for (int j = 0; j < 4; ++j) acc[i][j] = (f32x4)(0.0f);

  for (int k0 = 0; k0 < MID_; k0 += 32) {
#pragma unroll
    for (int q = 0; q < 2; ++q) {
      const int row = r0 + q * 16 + rrow;
      const int ig = min(i0 + row, N_ - 1);
      const int jg = min(j0 + row, N_ - 1);
      const int lb = (r0 + q * 16) * 32;
      gl16(&f_b[(size_t)ig * M_ + k0 + koff], &As[lb]);
      gl16(&f_b[(size_t)jg * M_ + MID_ + k0 + koff], &Bs[lb]);
    }
    __syncthreads();
    const int fr = lane & 15, qo = (lane >> 4) * 8;
    f16x8 af[4], bf[4];
#pragma unroll
    for (int i = 0; i < 4; ++i) {
      af[i] = *(const f16x8*)&As[(wm + 16 * i + fr) * 32 + qo];
      bf[i] = *(const f16x8*)&Bs[(wn + 16 * i + fr) * 32 + qo];
    }
#pragma unroll
    for (int i = 0; i < 4; ++i)
#pragma unroll
      for (int j = 0; j < 4; ++j)
        acc[i][j] = __builtin_amdgcn_mfma_f32_16x16x32_f16(af[i], bf[j], acc[i][j], 0, 0, 0);
    __syncthreads();
  }
  float* log_b = logits + (size_t)b * N_ * N_;
#pragma unroll
  for (int i = 0; i < 4; ++i) {
    const int ibase = i0 + wm + 16 * i + ((lane >> 4) * 4);
#pragma unroll
    for (int j = 0; j < 4; ++j) {
      const int jj = j0 + wn + 16 * j + (lane & 15);
      if (jj < N_) {
#pragma unroll
        for (int r = 0; r < 4; ++r) {
          const int ii = ibase + r;
          if (ii < N_) log_b[(size_t)ii * N_ + jj] = acc[i][j][r];
        }
      }
    }
  }
}

// ---------------------------------------------------------------------------
// K3: row softmax (576) — one wave per row; fp32 in, fp16 out.
// ---------------------------------------------------------------------------
__global__ __launch_bounds__(64) void k_softmax(
    const float* __restrict__ logits, f16* __restrict__ attn) {
  const int row = blockIdx.x;
  const float* p = logits + (size_t)row * N_;
  f16* o = attn + (size_t)row * N_;
  const int lane = threadIdx.x;
  float v[9];
  float mx = -INFINITY;
#pragma unroll
  for (int q = 0; q < 9; ++q) {
    v[q] = p[lane + q * 64];
    mx = fmaxf(mx, v[q]);
  }
#pragma unroll
  for (int off = 32; off > 0; off >>= 1) mx = fmaxf(mx, __shfl_down(mx, off));
  mx = __shfl(mx, 0);
  float s = 0.f;
#pragma unroll
  for (int q = 0; q < 9; ++q) {
    v[q] = __expf(v[q] - mx);
    s += v[q];
  }
#pragma unroll
  for (int off = 32; off > 0; off >>= 1) s += __shfl_down(s, off);
  s = __shfl(s, 0);
  const float inv = 1.0f / s;
#pragma unroll
  for (int q = 0; q < 9; ++q) o[lane + q * 64] = (f16)(v[q] * inv);
}

// ---------------------------------------------------------------------------
// K4: out[b][c][i] = alpha * sum_j attn[b][i][j]*camh[b][c][j] + camh[b][c][i]
// Single fp16 MFMA, pure DMA staging. Grid (16 ct, 5 it, 32 b).
// ---------------------------------------------------------------------------
__global__ __launch_bounds__(256) void k_out(
    const f16* __restrict__ camh, const f16* __restrict__ attn,
    const float* __restrict__ alpha_p, float* __restrict__ out) {
  const int ct = blockIdx.x;
  const int it = blockIdx.y;
  const int b  = blockIdx.z;
  __shared__ __align__(16) f16 As[128 * 32], Bs[128 * 32];
  const int t = threadIdx.x, lane = t & 63, w = t >> 6;
  const int wm = (w >> 1) * 64, wn = (w & 1) * 64;
  const int c0 = ct * 128, i0 = it * 128;
  const int rrow = lane >> 2;
  const int koff = (lane & 3) * 8;
  const int r0 = w * 32;
  const f16* camh_b = camh + (size_t)b * C_ * N_;
  const f16* attn_b = attn + (size_t)b * N_ * N_;

  f32x4 acc[4][4];
#pragma unroll
  for (int i = 0; i < 4; ++i)
#pragma unroll
    for (int j = 0; j < 4; ++j) acc[i][j] = (f32x4)(0.0f);

  for (int k0 = 0; k0 < N_; k0 += 32) {
#pragma unroll
    for (int q = 0; q < 2; ++q) {
      const int row = r0 + q * 16 + rrow;
      const int cg = c0 + row;
      const int ig = min(i0 + row, N_ - 1);
      const int lb = (r0 + q * 16) * 32;
      gl16(&camh_b[(size_t)cg * N_ + k0 + koff], &As[lb]);
      gl16(&attn_b[(size_t)ig * N_ + k0 + koff], &Bs[lb]);
    }
    __syncthreads();
    const int fr = lane & 15, qo = (lane >> 4) * 8;
    f16x8 af[4], bf[4];
#pragma unroll
    for (int i = 0; i < 4; ++i) {
      af[i] = *(const f16x8*)&As[(wm + 16 * i + fr) * 32 + qo];
      bf[i] = *(const f16x8*)&Bs[(wn + 16 * i + fr) * 32 + qo];
    }
#pragma unroll
    for (int i = 0; i < 4; ++i)
#pragma unroll
      for (int j = 0; j < 4; ++j)
        acc[i][j] = __builtin_amdgcn_mfma_f32_16x16x32_f16(af[i], bf[j], acc[i][j], 0, 0, 0);
    __syncthreads();
  }
  const float alpha = *alpha_p;
  float* out_b = out + (size_t)b * C_ * N_;
#pragma unroll
  for (int ii = 0; ii < 4; ++ii) {
    const int c = c0 + wm + 16 * ii + ((lane >> 4) * 4);
#pragma unroll
    for (int jj = 0; jj < 4; ++jj) {
      const int i = i0 + wn + 16 * jj + (lane & 15);
      if (i < N_) {
#pragma unroll
        for (int r = 0; r < 4; ++r) {
          const size_t off = (size_t)(c + r) * N_ + i;
          out_b[off] = alpha * acc[ii][jj][r] + (float)camh_b[off];
        }
      }
    }
  }
}

// ---------------------------------------------------------------------------
extern "C" void kernel_launch(void* const* d_in, const int* in_sizes, int n_in,
                              void* d_out, int out_size, void* d_ws,
                              size_t ws_size, hipStream_t stream) {
  const float* cam   = (const float*)d_in[0];
  const float* feat  = (const float*)d_in[1];
  const float* W1    = (const float*)d_in[2];
  const float* W2    = (const float*)d_in[3];
  const float* alpha = (const float*)d_in[4];
  float* out = (float*)d_out;

  // ws layout, 96.5 MB total (R2 proved >=124 MB available):
  //  [0, 75.5M)      fT fp16  -> logits fp32 [0,42.5M) -> camh fp16 [0,75.5M)
  //  [75.5M, 94.4M)  f12 fp16 -> attn fp16 [75.5M, 86.1M)
  //  [94.4M, 96.5M)  Wcat fp16
  char* ws = (char*)d_ws;
  f16*   fT     = (f16*)ws;
  f16*   f12    = (f16*)(ws + 75497472);
  f16*   Wc     = (f16*)(ws + 94371840);
  float* logits = (float*)ws;             // over fT (dead after k_f12)
  f16*   attn   = (f16*)(ws + 75497472);  // over f12 (dead after k_logits)
  f16*   camh   = (f16*)ws;               // over logits (dead after k_softmax)

  k_prep_w<<<dim3(512), 256, 0, stream>>>(W1, W2, Wc);
  k_prep_feat<<<dim3(32, 9, B_), 256, 0, stream>>>(feat, fT);
  k_f12<<<dim3(4, 144), 256, 0, stream>>>(fT, Wc, f12);
  k_logits<<<dim3(5, 5, B_), 256, 0, stream>>>(f12, logits);
  k_softmax<<<dim3(B_ * N_), 64, 0, stream>>>(logits, attn);
  k_prep_cam<<<dim3(18432), 256, 0, stream>>>(cam, camh);
  k_out<<<dim3(16, 5, B_), 256, 0, stream>>>(camh, attn, alpha, out);
}